// Round 16
// baseline (4195.968 us; speedup 1.0000x reference)
//
#include <hip/hip_runtime.h>
#include <cstddef>

// LSTM: x[64,512,512] f32, kernel[512,4096] f32, rec_kernel[1024,4096] f32,
// bias[4096] f32 -> h_last[64,1024] f32.
// R9 (5th submission; rounds 12-15 were infra failures): drain-free tagged
// publish + speculative consume.
//  - h published as per-dword (h_bf16<<16 | epoch) words; per-wave sentinel
//    stored immediately after (NO vmcnt drain, NO LDS vote). Tags catch any
//    store/sentinel reordering.
//  - Consumer issues all tagged h loads SPECULATIVELY at loop-top (flight
//    overlaps x-part MFMAs and the sentinel poll), then polls 64 sentinel
//    lines (1/lane, __all), then validates tags; masked retry loop with
//    s_sleep backoff re-reads only stale chunks. Sentinel gate prevents
//    R5-style retry flood; tags remove 2 of 3 serialized MALL RTs.
//  - Triple-buffered slabs; distance-2 transitivity (block-level read covers
//    all 64 same-mt producers) => tag-t readers done before slot reuse =>
//    retry always terminates. zsh parity-buffered, 1 barrier/step (R8).

namespace {
constexpr int cB = 64;
constexpr int cT = 512;
constexpr int cD = 512;
constexpr int cU = 1024;
constexpr int cG = 4096;   // 4*U
constexpr int NBLK = 256;
constexpr int NT = 256;
}

typedef __attribute__((ext_vector_type(8))) short   short8;
typedef __attribute__((ext_vector_type(8))) __bf16  bf16x8;
typedef __attribute__((ext_vector_type(4))) float   f32x4;

__device__ inline short f2bf(float f) {
  unsigned u = __float_as_uint(f);
  u += 0x7fffu + ((u >> 16) & 1u);   // round-to-nearest-even
  return (short)(u >> 16);
}

__device__ inline f32x4 mfma16(short8 a, short8 b, f32x4 c) {
  return __builtin_amdgcn_mfma_f32_16x16x32_bf16(
      __builtin_bit_cast(bf16x8, a), __builtin_bit_cast(bf16x8, b), c, 0, 0, 0);
}

__device__ inline float sigm(float x) { return 1.0f / (1.0f + __expf(-x)); }
__device__ inline float tanh_(float x) {
  float a = fabsf(x);
  float e = __expf(-2.0f * a);
  float t = (1.0f - e) / (1.0f + e);
  return x < 0.0f ? -t : t;
}

__device__ inline unsigned long long ald(const unsigned long long* p) {
  return __hip_atomic_load(p, __ATOMIC_RELAXED, __HIP_MEMORY_SCOPE_AGENT);
}

__global__ __launch_bounds__(NT, 1) void lstm_persist(
    const float* __restrict__ x, const float* __restrict__ wk,
    const float* __restrict__ wr, const float* __restrict__ bias,
    float* __restrict__ out, short* __restrict__ xbf,
    unsigned* hx, unsigned* sent, unsigned* flags) {
  const int tid  = threadIdx.x;
  const int wv   = tid >> 6;        // wave = K-slice owner (kh === wv mod 4)
  const int lane = tid & 63;
  const int n    = lane & 15;       // MFMA A row m / C col
  const int quad = lane >> 4;
  const int bid  = blockIdx.x;
  const int mt   = bid & 3;         // batch m-tile (16 rows each)
  const int cg   = bid >> 2;        // u-group 0..63 (16 u each)
  const int ub   = cg * 16;

  __shared__ float zsh[2][4 * 16 * 66]; // parity-buffered partial z planes

  // ---- phase 0: convert x to bf16 once (grid-stride) ----
  {
    const f32x4* xv = reinterpret_cast<const f32x4*>(x);
    short8* xo = reinterpret_cast<short8*>(xbf);
    const size_t nvec = (size_t)cB * cT * cD / 8;
    for (size_t i = (size_t)bid * NT + tid; i < nvec; i += (size_t)NBLK * NT) {
      f32x4 v0 = xv[2 * i];
      f32x4 v1 = xv[2 * i + 1];
      short8 s;
      s[0] = f2bf(v0[0]); s[1] = f2bf(v0[1]); s[2] = f2bf(v0[2]); s[3] = f2bf(v0[3]);
      s[4] = f2bf(v1[0]); s[5] = f2bf(v1[1]); s[6] = f2bf(v1[2]); s[7] = f2bf(v1[3]);
      xo[i] = s;
    }
  }

  // ---- time-invariant W fragments: Bf[i][g], kc = wv + 4*i, i=0..11 ----
  short8 Bf[12][4];
  #pragma unroll
  for (int i = 0; i < 12; ++i) {
    const int kc = wv + 4 * i;
    const int k0 = kc * 32 + quad * 8;
    #pragma unroll
    for (int g = 0; g < 4; ++g) {
      const int col = g * cU + ub + n;
      short8 b;
      #pragma unroll
      for (int j = 0; j < 8; ++j) {
        const int k = k0 + j;
        const float wgt = (k < cD) ? wk[(size_t)k * cG + col]
                                   : wr[(size_t)(k - cD) * cG + col];
        b[j] = f2bf(wgt);
      }
      Bf[i][g] = b;
    }
  }

  // ---- distributed epilogue mapping: thread -> (row, single u) ----
  const int erow = tid >> 4;        // 0..15
  const int eu   = tid & 15;        // 0..15
  const int hrow = mt * 16 + erow;
  const float bi  = bias[0 * cU + ub + eu];
  const float bff = bias[1 * cU + ub + eu];
  const float bc  = bias[2 * cU + ub + eu];
  const float bo  = bias[3 * cU + ub + eu];
  float cst = 0.0f;

  const int brow = mt * 16 + n;
  const short* xrow = xbf + (size_t)brow * cT * cD + quad * 8;

  // ---- initial full-grid barrier: xbf ready everywhere ----
  __builtin_amdgcn_fence(__ATOMIC_RELEASE, "agent");
  __syncthreads();
  if (tid == 0)
    __hip_atomic_store(flags + bid * 16, 1u, __ATOMIC_RELEASE,
                       __HIP_MEMORY_SCOPE_AGENT);
  if (wv == 0) {
    #pragma unroll
    for (int j = 0; j < 4; ++j) {
      const unsigned* fp = flags + (j * 64 + lane) * 16;
      while (__hip_atomic_load(fp, __ATOMIC_RELAXED,
                               __HIP_MEMORY_SCOPE_AGENT) < 1u) {}
    }
  }
  __syncthreads();
  __builtin_amdgcn_fence(__ATOMIC_ACQUIRE, "agent");

  // consumer chunk base (dword units within a slab buffer):
  // dword(u,row=n) = kh*2048 + (quad>>1)*1024 + mt*256 + n*16 + (quad&1)*8 + j
  const size_t cbase = (size_t)(quad >> 1) * 1024 + (size_t)mt * 256 +
                       (size_t)n * 16 + (size_t)(quad & 1) * 8;
  // poll line per lane: producer-wave (lane&3) of block p=lane>>2 in my set
  const unsigned* pollp;
  {
    const int p = lane >> 2, w = lane & 3;
    const int cgp = 2 * (wv + 4 * (p >> 1)) + (p & 1);
    pollp = sent + ((size_t)(cgp * 4 + mt) * 4 + w) * 32;
  }

  int rb = 1, wb = 1;   // triple-buffer read/write slots

  for (int t = 0; t < cT; ++t) {
    unsigned long long d[16][2];
    const unsigned tgt = (unsigned)t;
    const unsigned* hbb = hx + (size_t)rb * 65536;

    // ---- speculative tagged h loads (flight overlaps x-part + poll) ----
    if (t > 0) {
      #pragma unroll
      for (int i = 0; i < 8; ++i) {
        const unsigned long long* q = reinterpret_cast<const unsigned long long*>(
            hbb + cbase + (size_t)(wv + 4 * i) * 2048);
        d[2 * i][0]     = ald(q);
        d[2 * i][1]     = ald(q + 1);
        d[2 * i + 1][0] = ald(q + 2);
        d[2 * i + 1][1] = ald(q + 3);
      }
    }

    // ---- x-part (h-independent): kc = wv + 4*i, i=0..3 ----
    f32x4 acc[4] = {{0,0,0,0},{0,0,0,0},{0,0,0,0},{0,0,0,0}};
    {
      const short* xr = xrow + (size_t)t * cD;
      #pragma unroll
      for (int i = 0; i < 4; ++i) {
        short8 af = *reinterpret_cast<const short8*>(xr + (wv + 4 * i) * 32);
        #pragma unroll
        for (int g = 0; g < 4; ++g) acc[g] = mfma16(af, Bf[i][g], acc[g]);
      }
    }

    if (t > 0) {
      // ---- sentinel gate (throttle): 64 producer-wave lines, 1/lane ----
      while (!__all(__hip_atomic_load(pollp, __ATOMIC_RELAXED,
                                      __HIP_MEMORY_SCOPE_AGENT) >= tgt))
        __builtin_amdgcn_s_sleep(1);
      asm volatile("" ::: "memory");

      // ---- validate tags; masked retry for stragglers ----
      unsigned pend = 0;
      #pragma unroll
      for (int c = 0; c < 16; ++c) {
        const bool ok =
            ((unsigned)d[c][0] & 0xFFFFu) == tgt &&
            ((unsigned)(d[c][0] >> 32) & 0xFFFFu) == tgt &&
            ((unsigned)d[c][1] & 0xFFFFu) == tgt &&
            ((unsigned)(d[c][1] >> 32) & 0xFFFFu) == tgt;
        pend |= ok ? 0u : (1u << c);
      }
      while (__any(pend != 0u)) {
        __builtin_amdgcn_s_sleep(2);
        #pragma unroll
        for (int c = 0; c < 16; ++c)
          if (pend & (1u << c)) {
            const unsigned long long* q =
                reinterpret_cast<const unsigned long long*>(
                    hbb + cbase + (size_t)(wv + 4 * (c >> 1)) * 2048) +
                (c & 1) * 2;
            d[c][0] = ald(q);
            d[c][1] = ald(q + 1);
          }
        unsigned np = 0;
        #pragma unroll
        for (int c = 0; c < 16; ++c)
          if (pend & (1u << c)) {
            const bool ok =
                ((unsigned)d[c][0] & 0xFFFFu) == tgt &&
                ((unsigned)(d[c][0] >> 32) & 0xFFFFu) == tgt &&
                ((unsigned)d[c][1] & 0xFFFFu) == tgt &&
                ((unsigned)(d[c][1] >> 32) & 0xFFFFu) == tgt;
            np |= ok ? 0u : (1u << c);
          }
        pend = np;
      }

      // ---- repack (strip tags) + h-part MFMAs ----
      #pragma unroll
      for (int i = 0; i < 8; ++i) {
        short8 hr;
        hr[0] = (short)(d[2 * i][0] >> 16);
        hr[1] = (short)(d[2 * i][0] >> 48);
        hr[2] = (short)(d[2 * i][1] >> 16);
        hr[3] = (short)(d[2 * i][1] >> 48);
        hr[4] = (short)(d[2 * i + 1][0] >> 16);
        hr[5] = (short)(d[2 * i + 1][0] >> 48);
        hr[6] = (short)(d[2 * i + 1][1] >> 16);
        hr[7] = (short)(d[2 * i + 1][1] >> 48);
        #pragma unroll
        for (int g = 0; g < 4; ++g)
          acc[g] = mfma16(hr, Bf[4 + i][g], acc[g]);
      }
    }

    // ---- per-wave partial z to zsh[par] plane wv ----
    const int par = t & 1;
    #pragma unroll
    for (int g = 0; g < 4; ++g)
      #pragma unroll
      for (int r = 0; r < 4; ++r)
        zsh[par][(wv * 16 + quad * 4 + r) * 66 + g * 16 + n] = acc[g][r];
    __syncthreads();   // the only barrier per step

    // ---- distributed epilogue: 1 u per thread; sum 4 wave-planes ----
    const float* zp = zsh[par];
    float z[4];
    #pragma unroll
    for (int g = 0; g < 4; ++g)
      z[g] = zp[(erow) * 66 + g * 16 + eu] +
             zp[(16 + erow) * 66 + g * 16 + eu] +
             zp[(32 + erow) * 66 + g * 16 + eu] +
             zp[(48 + erow) * 66 + g * 16 + eu];
    const float ig = sigm(z[0] + bi);
    const float fg = sigm(z[1] + bff);
    const float gg = tanh_(z[2] + bc);
    const float og = sigm(z[3] + bo);
    cst = fg * cst + ig * gg;
    const float h = og * tanh_(cst);

    if (t == cT - 1) {
      out[(size_t)hrow * cU + ub + eu] = h;
    } else {
      // tagged publish (fire-and-forget) + immediate per-wave sentinel
      const unsigned dw =
          ((unsigned)(unsigned short)f2bf(h) << 16) | (unsigned)(t + 1);
      __hip_atomic_store(hx + (size_t)wb * 65536 +
                             (size_t)(cg * 4 + mt) * 256 + tid,
                         dw, __ATOMIC_RELAXED, __HIP_MEMORY_SCOPE_AGENT);
      if (lane == 0)
        __hip_atomic_store(sent + ((size_t)(cg * 4 + mt) * 4 + wv) * 32,
                           (unsigned)(t + 1), __ATOMIC_RELAXED,
                           __HIP_MEMORY_SCOPE_AGENT);
      rb = wb;
      wb = (wb == 2) ? 0 : wb + 1;
    }
  }
}

extern "C" void kernel_launch(void* const* d_in, const int* in_sizes, int n_in,
                              void* d_out, int out_size, void* d_ws, size_t ws_size,
                              hipStream_t stream) {
  const float* x    = (const float*)d_in[0];
  const float* wk   = (const float*)d_in[1];
  const float* wr   = (const float*)d_in[2];
  const float* bias = (const float*)d_in[3];
  float* out = (float*)d_out;

  char* ws = (char*)d_ws;
  unsigned* flags = (unsigned*)ws;                 // 256 slots x 64B = 16 KB
  unsigned* sent  = (unsigned*)(ws + 16384);       // 1024 wave-lines x 128B
  unsigned* hx    = (unsigned*)(ws + 147456);      // 3 x 256KB tagged h slabs
  short* xbf = (short*)(ws + 933888);              // x bf16, 32 MB

  // zero flags + sentinels. hx needs no clear: poisoned tag 0xAAAA never
  // equals any expected epoch 1..511, and slot s is written with tag t
  // before any consumer expects tag t there.
  hipMemsetAsync(ws, 0, 147456, stream);

  lstm_persist<<<dim3(NBLK), dim3(NT), 0, stream>>>(
      x, wk, wr, bias, out, xbf, hx, sent, flags);
}

// Round 17
// 2345.632 us; speedup vs baseline: 1.7888x; 1.7888x over previous
//
#include <hip/hip_runtime.h>
#include <cstddef>

// LSTM: x[64,512,512] f32, kernel[512,4096] f32, rec_kernel[1024,4096] f32,
// bias[4096] f32 -> h_last[64,1024] f32.
// R10: poll decongestion on the R7/R8 skeleton.
// Evidence: R6=2252, R7=2157, R8=2250, R9=4196 (flood), R5=4334 (flood).
// Mechanism tweaks move <5%; traffic floods cost 2x. Hypothesis: the ~4.2us
// step is MALL RT inflated by poll-probe congestion on hot signal lines
// (R7: 256 spinners/line @ sleep(1)). This round cuts probe traffic ~60x:
//  - wave0-only polling (64 lanes x 1 block-sentinel line each); waves 1-3
//    released via LDS go_flag relay (R7-proven pattern).
//  - sleep(8) backoff + per-lane done-mask: ~16x fewer probes, <=512cy added
//    detect latency.
//  - RMW-free publish (R8): per-wave vmcnt(0) drain -> LDS vote -> 4th wave
//    stores ONE plain sentinel to the block's private 128B line.
//  - R8's drain overlap (h-store -> x-part(t+1) -> vmcnt(0)), parity zsh,
//    1 barrier/step, triple-buffered h.
// Safety: sentinel(t) from block B => B's h(t) stores drained => B's reads
// of h(t-1) complete (data-dep before stores). go_flag chain inducts to t=0
// (no circular wait). Slot reuse: writer at t passed wait(t) => all same-mt
// blocks published t-1 => their consumption of h(t-2) & earlier done =>
// triple buffer is safe with margin (double would suffice; triple kept).

namespace {
constexpr int cB = 64;
constexpr int cT = 512;
constexpr int cD = 512;
constexpr int cU = 1024;
constexpr int cG = 4096;   // 4*U
constexpr int NBLK = 256;
constexpr int NT = 256;
}

typedef __attribute__((ext_vector_type(8))) short   short8;
typedef __attribute__((ext_vector_type(8))) __bf16  bf16x8;
typedef __attribute__((ext_vector_type(4))) float   f32x4;

__device__ inline short f2bf(float f) {
  unsigned u = __float_as_uint(f);
  u += 0x7fffu + ((u >> 16) & 1u);   // round-to-nearest-even
  return (short)(u >> 16);
}

__device__ inline f32x4 mfma16(short8 a, short8 b, f32x4 c) {
  return __builtin_amdgcn_mfma_f32_16x16x32_bf16(
      __builtin_bit_cast(bf16x8, a), __builtin_bit_cast(bf16x8, b), c, 0, 0, 0);
}

__device__ inline float sigm(float x) { return 1.0f / (1.0f + __expf(-x)); }
__device__ inline float tanh_(float x) {
  float a = fabsf(x);
  float e = __expf(-2.0f * a);
  float t = (1.0f - e) / (1.0f + e);
  return x < 0.0f ? -t : t;
}

__global__ __launch_bounds__(NT, 1) void lstm_persist(
    const float* __restrict__ x, const float* __restrict__ wk,
    const float* __restrict__ wr, const float* __restrict__ bias,
    float* __restrict__ out, short* __restrict__ xbf,
    short* hx, unsigned* sent, unsigned* flags) {
  const int tid  = threadIdx.x;
  const int wv   = tid >> 6;        // wave = K-slice owner (kc === wv mod 4)
  const int lane = tid & 63;
  const int n    = lane & 15;       // MFMA A row m / C col
  const int quad = lane >> 4;
  const int bid  = blockIdx.x;
  const int mt   = bid & 3;         // batch m-tile (16 rows each)
  const int cg   = bid >> 2;        // u-group 0..63 (16 u each)
  const int ub   = cg * 16;

  __shared__ float zsh[2][4 * 16 * 66]; // parity-buffered partial z planes
  __shared__ unsigned done;             // monotonic LDS vote counter
  __shared__ unsigned go_flag;          // LDS epoch relay (monotonic)

  if (tid == 0) { done = 0u; go_flag = 0u; }

  // ---- phase 0: convert x to bf16 once (grid-stride) ----
  {
    const f32x4* xv = reinterpret_cast<const f32x4*>(x);
    short8* xo = reinterpret_cast<short8*>(xbf);
    const size_t nvec = (size_t)cB * cT * cD / 8;
    for (size_t i = (size_t)bid * NT + tid; i < nvec; i += (size_t)NBLK * NT) {
      f32x4 v0 = xv[2 * i];
      f32x4 v1 = xv[2 * i + 1];
      short8 s;
      s[0] = f2bf(v0[0]); s[1] = f2bf(v0[1]); s[2] = f2bf(v0[2]); s[3] = f2bf(v0[3]);
      s[4] = f2bf(v1[0]); s[5] = f2bf(v1[1]); s[6] = f2bf(v1[2]); s[7] = f2bf(v1[3]);
      xo[i] = s;
    }
  }

  // ---- time-invariant W fragments: Bf[i][g], kc = wv + 4*i, i=0..11 ----
  short8 Bf[12][4];
  #pragma unroll
  for (int i = 0; i < 12; ++i) {
    const int kc = wv + 4 * i;
    const int k0 = kc * 32 + quad * 8;
    #pragma unroll
    for (int g = 0; g < 4; ++g) {
      const int col = g * cU + ub + n;
      short8 b;
      #pragma unroll
      for (int j = 0; j < 8; ++j) {
        const int k = k0 + j;
        const float wgt = (k < cD) ? wk[(size_t)k * cG + col]
                                   : wr[(size_t)(k - cD) * cG + col];
        b[j] = f2bf(wgt);
      }
      Bf[i][g] = b;
    }
  }

  // ---- distributed epilogue mapping: thread -> (row, single u) ----
  const int erow = tid >> 4;        // 0..15
  const int eu   = tid & 15;        // 0..15
  const int hrow = mt * 16 + erow;
  const float bi  = bias[0 * cU + ub + eu];
  const float bff = bias[1 * cU + ub + eu];
  const float bc  = bias[2 * cU + ub + eu];
  const float bo  = bias[3 * cU + ub + eu];
  float cst = 0.0f;

  const int brow = mt * 16 + n;
  const short* xrow = xbf + (size_t)brow * cT * cD + quad * 8;

  // ---- initial full-grid barrier: xbf ready everywhere ----
  __builtin_amdgcn_fence(__ATOMIC_RELEASE, "agent");
  __syncthreads();
  if (tid == 0)
    __hip_atomic_store(flags + bid * 16, 1u, __ATOMIC_RELEASE,
                       __HIP_MEMORY_SCOPE_AGENT);
  if (wv == 0) {
    #pragma unroll
    for (int j = 0; j < 4; ++j) {
      const unsigned* fp = flags + (j * 64 + lane) * 16;
      while (__hip_atomic_load(fp, __ATOMIC_RELAXED,
                               __HIP_MEMORY_SCOPE_AGENT) < 1u) {}
    }
  }
  __syncthreads();
  __builtin_amdgcn_fence(__ATOMIC_ACQUIRE, "agent");

  const unsigned long long* hxu =
      reinterpret_cast<const unsigned long long*>(hx);
  // consumer h-load offset within a buffer (ull units), layout [cg'][mt][r][u']
  const size_t hoff = (size_t)(quad >> 1) * 256 + (size_t)mt * 64 +
                      (size_t)n * 4 + (size_t)(quad & 1) * 2;
  // producer sentinel line (128B each, one per block)
  unsigned* sentp = sent + (size_t)(cg * 4 + mt) * 32;
  // wave0 poll line: lane l watches block (cg'=l, mt) — covers all 64
  const unsigned* pollp = sent + ((size_t)(lane * 4 + mt)) * 32;

  // ---- prologue: x-part for t=0 ----
  f32x4 acc[4] = {{0,0,0,0},{0,0,0,0},{0,0,0,0},{0,0,0,0}};
  {
    const short* xr = xrow;
    #pragma unroll
    for (int i = 0; i < 4; ++i) {
      short8 af = *reinterpret_cast<const short8*>(xr + (wv + 4 * i) * 32);
      #pragma unroll
      for (int g = 0; g < 4; ++g) acc[g] = mfma16(af, Bf[i][g], acc[g]);
    }
  }

  int wb = 0, rb = 0;   // triple-buffer write/read indices

  for (int t = 0; t < cT; ++t) {
    if (t > 0) {
      // ---- decongested arrival wait ----
      // wave0: 64 lanes x 1 block-sentinel line, done-mask + sleep(8)
      // (~16x fewer probes than sleep(1); ~60x less line traffic than R7).
      // waves 1-3: spin on LDS go_flag (zero MALL traffic).
      const unsigned tgt = (unsigned)t;
      if (wv == 0) {
        bool rdy = false;
        while (true) {
          if (!rdy)
            rdy = __hip_atomic_load(pollp, __ATOMIC_RELAXED,
                                    __HIP_MEMORY_SCOPE_AGENT) >= tgt;
          if (__all(rdy)) break;
          __builtin_amdgcn_s_sleep(8);
        }
        __hip_atomic_store(&go_flag, tgt, __ATOMIC_RELEASE,
                           __HIP_MEMORY_SCOPE_WORKGROUP);
      } else {
        while (__hip_atomic_load(&go_flag, __ATOMIC_ACQUIRE,
                                 __HIP_MEMORY_SCOPE_WORKGROUP) < tgt) {}
      }
      asm volatile("" ::: "memory");   // no load hoisting above the wait

      // ---- h A-frags straight to registers (buffer rb) ----
      const unsigned long long* hb = hxu + (size_t)rb * 16384 + hoff;
      unsigned long long hv[16];
      #pragma unroll
      for (int i = 0; i < 8; ++i) {
        const int off = (wv + 4 * i) * 512;
        hv[2 * i]     = __hip_atomic_load(hb + off,     __ATOMIC_RELAXED,
                                          __HIP_MEMORY_SCOPE_AGENT);
        hv[2 * i + 1] = __hip_atomic_load(hb + off + 1, __ATOMIC_RELAXED,
                                          __HIP_MEMORY_SCOPE_AGENT);
      }
      #pragma unroll
      for (int i = 0; i < 8; ++i) {
        union { unsigned long long q[2]; short8 s; } u_;
        u_.q[0] = hv[2 * i]; u_.q[1] = hv[2 * i + 1];
        #pragma unroll
        for (int g = 0; g < 4; ++g)
          acc[g] = mfma16(u_.s, Bf[4 + i][g], acc[g]);
      }
    }

    // ---- per-wave partial z to zsh[par] plane wv ----
    const int par = t & 1;
    #pragma unroll
    for (int g = 0; g < 4; ++g)
      #pragma unroll
      for (int r = 0; r < 4; ++r)
        zsh[par][(wv * 16 + quad * 4 + r) * 66 + g * 16 + n] = acc[g][r];
    __syncthreads();   // per-instance rendezvous: siblings aligned here

    // ---- distributed epilogue: 1 u per thread; sum 4 wave-planes ----
    const float* zp = zsh[par];
    float z[4];
    #pragma unroll
    for (int g = 0; g < 4; ++g)
      z[g] = zp[(erow) * 66 + g * 16 + eu] +
             zp[(16 + erow) * 66 + g * 16 + eu] +
             zp[(32 + erow) * 66 + g * 16 + eu] +
             zp[(48 + erow) * 66 + g * 16 + eu];
    const float ig = sigm(z[0] + bi);
    const float fg = sigm(z[1] + bff);
    const float gg = tanh_(z[2] + bc);
    const float og = sigm(z[3] + bo);
    cst = fg * cst + ig * gg;
    const float h = og * tanh_(cst);

    if (t == cT - 1) {
      out[(size_t)hrow * cU + ub + eu] = h;
    } else {
      // issue contiguous 512B block publish (2B per thread)
      __hip_atomic_store(hx + (size_t)wb * 65536 +
                             (size_t)(cg * 4 + mt) * 256 + tid,
                         f2bf(h), __ATOMIC_RELAXED, __HIP_MEMORY_SCOPE_AGENT);

      // ---- x-part for t+1 overlaps the store drain ----
      #pragma unroll
      for (int g = 0; g < 4; ++g) acc[g] = f32x4{0, 0, 0, 0};
      {
        const short* xr = xrow + (size_t)(t + 1) * cD;
        #pragma unroll
        for (int i = 0; i < 4; ++i) {
          short8 af = *reinterpret_cast<const short8*>(xr + (wv + 4 * i) * 32);
          #pragma unroll
          for (int g = 0; g < 4; ++g) acc[g] = mfma16(af, Bf[i][g], acc[g]);
        }
      }

      // drain this wave's stores, then LDS vote; 4th wave stores sentinel
      asm volatile("s_waitcnt vmcnt(0)" ::: "memory");
      if (lane == 0) {
        const unsigned old = __hip_atomic_fetch_add(
            &done, 1u, __ATOMIC_ACQ_REL, __HIP_MEMORY_SCOPE_WORKGROUP);
        if ((old & 3u) == 3u)
          __hip_atomic_store(sentp, (old >> 2) + 1u, __ATOMIC_RELAXED,
                             __HIP_MEMORY_SCOPE_AGENT);
      }
      rb = wb;
      wb = (wb == 2) ? 0 : wb + 1;
    }
  }
}

extern "C" void kernel_launch(void* const* d_in, const int* in_sizes, int n_in,
                              void* d_out, int out_size, void* d_ws, size_t ws_size,
                              hipStream_t stream) {
  const float* x    = (const float*)d_in[0];
  const float* wk   = (const float*)d_in[1];
  const float* wr   = (const float*)d_in[2];
  const float* bias = (const float*)d_in[3];
  float* out = (float*)d_out;

  char* ws = (char*)d_ws;
  unsigned* flags = (unsigned*)ws;                 // 256 slots x 64B = 16 KB
  unsigned* sent  = (unsigned*)(ws + 16384);       // 256 blocks x 128B = 32 KB
  short* hx  = (short*)(ws + 49152);               // 3 x 128KB bf16 h buffers
  short* xbf = (short*)(ws + 49152 + 393216);      // x bf16, 32 MB

  // zero flags (startup barrier) + sentinels (epoch 0 < any target 1..511).
  hipMemsetAsync(ws, 0, 49152, stream);

  lstm_persist<<<dim3(NBLK), dim3(NT), 0, stream>>>(
      x, wk, wr, bias, out, xbf, hx, sent, flags);
}

// Round 20
// 1656.733 us; speedup vs baseline: 2.5327x; 1.4158x over previous
//
#include <hip/hip_runtime.h>
#include <cstddef>

// LSTM: x[64,512,512] f32, kernel[512,4096] f32, rec_kernel[1024,4096] f32,
// bias[4096] f32 -> h_last[64,1024] f32.
// R11 (3rd submission; rounds 18-19 were infra failures): coalesced h fan-in
// on the R7 (best, 2157us) skeleton.
// Evidence: R6=2252, R7=2157, R8=2250, R10=2346 (sync-mechanism variants all
// within 5%); R5=4334, R9=4196 (data-poll floods 2x). The invariant residual
// is the h READ path: 16 scattered 8B agent-atomic loads/lane/step = ~1M
// uncoalesced MALL requests/step. This round changes ONLY that:
//  - h slab relaid as [kc=32][mt=4][row=16][kdim=32] bf16: a wave's fragment
//    tile is 1KB contiguous; lane (n,quad) does ONE global_load_dwordx4
//    sc0 sc1 at n*64+quad*16. 8 batch loads/wave/step, one vmcnt(0) +
//    sched_barrier(0) (rule #18), then MFMAs. ~16x fewer, line-granular
//    MALL requests.
//  - producer publishes the same values at the remapped address (2B/thread
//    agent-scope store; wave covers contiguous 32B runs).
//  - sync/tiling/epilogue = byte-for-byte R7: per-wave fetch_add counters
//    (target 64t), wave0 lanes<4 sleep(1) poll, LDS go_flag relay, single
//    barrier/step, double-buffered slabs (R7's WAR proof unchanged).

namespace {
constexpr int cB = 64;
constexpr int cT = 512;
constexpr int cD = 512;
constexpr int cU = 1024;
constexpr int cG = 4096;   // 4*U
constexpr int NBLK = 256;
constexpr int NT = 256;
}

typedef __attribute__((ext_vector_type(8))) short   short8;
typedef __attribute__((ext_vector_type(8))) __bf16  bf16x8;
typedef __attribute__((ext_vector_type(4))) float   f32x4;

__device__ inline short f2bf(float f) {
  unsigned u = __float_as_uint(f);
  u += 0x7fffu + ((u >> 16) & 1u);   // round-to-nearest-even
  return (short)(u >> 16);
}

__device__ inline f32x4 mfma16(short8 a, short8 b, f32x4 c) {
  return __builtin_amdgcn_mfma_f32_16x16x32_bf16(
      __builtin_bit_cast(bf16x8, a), __builtin_bit_cast(bf16x8, b), c, 0, 0, 0);
}

__device__ inline float sigm(float x) { return 1.0f / (1.0f + __expf(-x)); }
__device__ inline float tanh_(float x) {
  float a = fabsf(x);
  float e = __expf(-2.0f * a);
  float t = (1.0f - e) / (1.0f + e);
  return x < 0.0f ? -t : t;
}

// 16B MALL-coherent load (bypasses L1/L2 via sc0 sc1). Caller must
// s_waitcnt vmcnt(0) + sched_barrier(0) before consuming (rule #18).
__device__ inline f32x4 ald16(const void* p) {
  f32x4 r;
  asm volatile("global_load_dwordx4 %0, %1, off sc0 sc1"
               : "=&v"(r) : "v"(p));
  return r;
}

__global__ __launch_bounds__(NT, 1) void lstm_persist(
    const float* __restrict__ x, const float* __restrict__ wk,
    const float* __restrict__ wr, const float* __restrict__ bias,
    float* __restrict__ out, short* __restrict__ xbf,
    short* hx, unsigned* cnt, unsigned* flags) {
  const int tid  = threadIdx.x;
  const int wv   = tid >> 6;        // wave = K-slice owner (kc === wv mod 4)
  const int lane = tid & 63;
  const int n    = lane & 15;       // MFMA A row m / C col
  const int quad = lane >> 4;
  const int bid  = blockIdx.x;
  const int mt   = bid & 3;         // batch m-tile (16 rows each)
  const int cg   = bid >> 2;        // u-group 0..63 (16 u each)
  const int ub   = cg * 16;

  __shared__ float zsh[4 * 16 * 66]; // [wave][row][gate*16+u], pad 66
  __shared__ unsigned go_flag;       // LDS epoch relay (monotonic)

  if (tid == 0) go_flag = 0u;

  // ---- phase 0: convert x to bf16 once (grid-stride) ----
  {
    const f32x4* xv = reinterpret_cast<const f32x4*>(x);
    short8* xo = reinterpret_cast<short8*>(xbf);
    const size_t nvec = (size_t)cB * cT * cD / 8;
    for (size_t i = (size_t)bid * NT + tid; i < nvec; i += (size_t)NBLK * NT) {
      f32x4 v0 = xv[2 * i];
      f32x4 v1 = xv[2 * i + 1];
      short8 s;
      s[0] = f2bf(v0[0]); s[1] = f2bf(v0[1]); s[2] = f2bf(v0[2]); s[3] = f2bf(v0[3]);
      s[4] = f2bf(v1[0]); s[5] = f2bf(v1[1]); s[6] = f2bf(v1[2]); s[7] = f2bf(v1[3]);
      xo[i] = s;
    }
  }

  // ---- time-invariant W fragments: Bf[i][g], kc = wv + 4*i, i=0..11 ----
  // B[k][n]: n = lane&15 col-in-tile, k = quad*8 + j. Gate g col = g*cU+ub+n.
  short8 Bf[12][4];
  #pragma unroll
  for (int i = 0; i < 12; ++i) {
    const int kc = wv + 4 * i;
    const int k0 = kc * 32 + quad * 8;
    #pragma unroll
    for (int g = 0; g < 4; ++g) {
      const int col = g * cU + ub + n;
      short8 b;
      #pragma unroll
      for (int j = 0; j < 8; ++j) {
        const int k = k0 + j;
        const float wgt = (k < cD) ? wk[(size_t)k * cG + col]
                                   : wr[(size_t)(k - cD) * cG + col];
        b[j] = f2bf(wgt);
      }
      Bf[i][g] = b;
    }
  }

  // ---- distributed epilogue mapping: thread -> (row, single u) ----
  const int erow = tid >> 4;        // 0..15
  const int eu   = tid & 15;        // 0..15
  const int hrow = mt * 16 + erow;  // global batch row this thread owns
  const float bi  = bias[0 * cU + ub + eu];
  const float bff = bias[1 * cU + ub + eu];
  const float bc  = bias[2 * cU + ub + eu];
  const float bo  = bias[3 * cU + ub + eu];
  float cst = 0.0f;

  // A-frag addressing for x: A[m][k], m = lane&15 -> batch row, k = quad*8+j
  const int brow = mt * 16 + n;
  const short* xrow = xbf + (size_t)brow * cT * cD + quad * 8;

  // ---- initial full-grid barrier: xbf ready everywhere ----
  __builtin_amdgcn_fence(__ATOMIC_RELEASE, "agent");
  __syncthreads();
  if (tid == 0)
    __hip_atomic_store(flags + bid * 16, 1u, __ATOMIC_RELEASE,
                       __HIP_MEMORY_SCOPE_AGENT);
  if (wv == 0) {
    #pragma unroll
    for (int j = 0; j < 4; ++j) {
      const unsigned* fp = flags + (j * 64 + lane) * 16;
      while (__hip_atomic_load(fp, __ATOMIC_RELAXED,
                               __HIP_MEMORY_SCOPE_AGENT) < 1u) {}
    }
  }
  __syncthreads();
  __builtin_amdgcn_fence(__ATOMIC_ACQUIRE, "agent");

  const int mygrp = mt * 4 + (cg >> 4);   // this block's producer counter
  // consumer h-load base: slab layout [kc=32][mt=4][r=16][kdim=32] bf16.
  // lane (n,quad), load i -> byte off = (wv+4i)*4096 + mt*1024 + n*64 + quad*16
  const char* hcons = reinterpret_cast<const char*>(hx) +
                      (size_t)wv * 4096 + (size_t)mt * 1024 +
                      (size_t)n * 64 + (size_t)quad * 16;
  // producer store index (shorts): h[row erow][u=ub+eu] ->
  // kc = cg>>1, kdim = (cg&1)*16 + eu
  const size_t ppub = ((size_t)(cg >> 1) * 4 + mt) * 512 +
                      (size_t)erow * 32 + (size_t)(cg & 1) * 16 + eu;

  for (int t = 0; t < cT; ++t) {
    f32x4 acc[4] = {{0,0,0,0},{0,0,0,0},{0,0,0,0},{0,0,0,0}};

    // x-part (h-independent): kc = wv + 4*i, i=0..3 (kc < 16)
    const short* xr = xrow + (size_t)t * cD;
    #pragma unroll
    for (int i = 0; i < 4; ++i) {
      short8 af = *reinterpret_cast<const short8*>(xr + (wv + 4 * i) * 32);
      #pragma unroll
      for (int g = 0; g < 4; ++g) acc[g] = mfma16(af, Bf[i][g], acc[g]);
    }

    if (t > 0) {
      // ---- arrival wait (R7-exact): wave0 polls 4 counters, sleep(1);
      //      waves 1-3 released via LDS go_flag relay ----
      if (wv == 0) {
        if (lane < 4) {
          const unsigned* cp = cnt + (mt * 4 + lane) * 32;
          const unsigned tgt = 64u * (unsigned)t;
          while (__hip_atomic_load(cp, __ATOMIC_RELAXED,
                                   __HIP_MEMORY_SCOPE_AGENT) < tgt)
            __builtin_amdgcn_s_sleep(1);
        }
        __hip_atomic_store(&go_flag, (unsigned)t, __ATOMIC_RELEASE,
                           __HIP_MEMORY_SCOPE_WORKGROUP);
      } else {
        while (__hip_atomic_load(&go_flag, __ATOMIC_ACQUIRE,
                                 __HIP_MEMORY_SCOPE_WORKGROUP) < (unsigned)t) {}
      }
      asm volatile("" ::: "memory");   // no load hoisting above the wait

      // ---- coalesced h loads: 8 x dwordx4, wave-contiguous 1KB tiles ----
      const char* hb = hcons + (size_t)((t - 1) & 1) * 131072;
      f32x4 hv[8];
      #pragma unroll
      for (int i = 0; i < 8; ++i)
        hv[i] = ald16(hb + (size_t)i * 16384);
      asm volatile("s_waitcnt vmcnt(0)" ::: "memory");
      __builtin_amdgcn_sched_barrier(0);   // rule #18: pin MFMAs after wait

      #pragma unroll
      for (int i = 0; i < 8; ++i) {
        short8 hr = __builtin_bit_cast(short8, hv[i]);
        #pragma unroll
        for (int g = 0; g < 4; ++g)
          acc[g] = mfma16(hr, Bf[4 + i][g], acc[g]);
      }
    }

    // ---- per-wave partial z to zsh plane wv ----
    // C/D layout: col = n, row = quad*4 + r
    #pragma unroll
    for (int g = 0; g < 4; ++g)
      #pragma unroll
      for (int r = 0; r < 4; ++r)
        zsh[(wv * 16 + quad * 4 + r) * 66 + g * 16 + n] = acc[g][r];
    __syncthreads();   // the ONLY barrier per step

    // ---- distributed epilogue: 1 u per thread; sum 4 wave-planes ----
    float z[4];
    #pragma unroll
    for (int g = 0; g < 4; ++g)
      z[g] = zsh[(erow) * 66 + g * 16 + eu] +
             zsh[(16 + erow) * 66 + g * 16 + eu] +
             zsh[(32 + erow) * 66 + g * 16 + eu] +
             zsh[(48 + erow) * 66 + g * 16 + eu];
    const float ig = sigm(z[0] + bi);
    const float fg = sigm(z[1] + bff);
    const float gg = tanh_(z[2] + bc);
    const float og = sigm(z[3] + bo);
    cst = fg * cst + ig * gg;
    const float h = og * tanh_(cst);

    if (t == cT - 1) {
      out[(size_t)hrow * cU + ub + eu] = h;
    } else {
      // publish into [kc][mt][r][kdim] slab (2B per thread)
      __hip_atomic_store(hx + (size_t)(t & 1) * 65536 + ppub, f2bf(h),
                         __ATOMIC_RELAXED, __HIP_MEMORY_SCOPE_AGENT);
      // per-wave drain + signal (R7-exact)
      asm volatile("s_waitcnt vmcnt(0)" ::: "memory");
      if (lane == 0)
        __hip_atomic_fetch_add(cnt + mygrp * 32, 1u, __ATOMIC_RELAXED,
                               __HIP_MEMORY_SCOPE_AGENT);
    }
  }
}

extern "C" void kernel_launch(void* const* d_in, const int* in_sizes, int n_in,
                              void* d_out, int out_size, void* d_ws, size_t ws_size,
                              hipStream_t stream) {
  const float* x    = (const float*)d_in[0];
  const float* wk   = (const float*)d_in[1];
  const float* wr   = (const float*)d_in[2];
  const float* bias = (const float*)d_in[3];
  float* out = (float*)d_out;

  char* ws = (char*)d_ws;
  unsigned* flags = (unsigned*)ws;                 // 256 slots x 64B = 16 KB
  unsigned* cnt   = (unsigned*)(ws + 16384);       // 16 counters x 128B = 2 KB
  short* hx  = (short*)(ws + 18432);               // 2 x 128KB bf16 h slabs
  short* xbf = (short*)(ws + 18432 + 262144);      // x bf16, 32 MB

  // zero flags (startup barrier) + counters (monotonic arrival counts).
  hipMemsetAsync(ws, 0, 18432, stream);

  lstm_persist<<<dim3(NBLK), dim3(NT), 0, stream>>>(
      x, wk, wr, bias, out, xbf, hx, cnt, flags);
}